// Round 15
// baseline (462.311 us; speedup 1.0000x reference)
//
#include <hip/hip_runtime.h>
#include <hip/hip_fp16.h>
#include <stdint.h>

#define HD 512
#define TILE 64
#define NSTEPS 1
#define NT 1024

typedef float    f32x16 __attribute__((ext_vector_type(16)));
typedef float    f32x4  __attribute__((ext_vector_type(4)));
typedef _Float16 f16x8  __attribute__((ext_vector_type(8)));

typedef __attribute__((address_space(3))) uint32_t lds_u32;
typedef __attribute__((address_space(1))) const uint32_t glb_u32;

__device__ __forceinline__ float tanh_fast(float x) {
    float e = __builtin_amdgcn_exp2f(x * 2.885390081777927f);   // e^{2x}
    return __builtin_fmaf(-2.f, __builtin_amdgcn_rcpf(1.f + e), 1.f);
}

__device__ __forceinline__ uint32_t pkh(float lo, float hi) {
    return __builtin_bit_cast(uint32_t, __builtin_amdgcn_cvt_pkrtz(lo, hi));
}

// Packed fragment-ordered weights:
//   WP[idx], idx = ((qb*32 + kk)*64 + lane)*8 + j
//   value = W[p][q],  p = kk*16 + (lane>>5)*8 + j,  q = qb*32 + (lane&31)
__global__ void prep_kernel(const float* __restrict__ W1,
                            const float* __restrict__ W0,
                            const float* __restrict__ Wl,
                            __half* __restrict__ W1P,
                            __half* __restrict__ MP) {
    int idx = blockIdx.x * 256 + threadIdx.x;     // 0 .. 512*512-1
    int j    = idx & 7;
    int lane = (idx >> 3) & 63;
    int kk   = (idx >> 9) & 31;
    int qb   = idx >> 14;
    int p = kk * 16 + (lane >> 5) * 8 + j;
    int q = qb * 32 + (lane & 31);
    float w = W1[p * HD + q];
    float c = W0[HD + p]     * Wl[q * 3 + 0]
            + W0[2 * HD + p] * Wl[q * 3 + 1]
            + W0[3 * HD + p] * Wl[q * 3 + 2];
    W1P[idx] = __float2half(w);
    MP[idx]  = __float2half(w * c);
}

union U4 { uint4 q; f16x8 v; __half2 h[4]; uint32_t u[4]; };

__global__ __launch_bounds__(NT, 4)
void ode_kernel(const float* __restrict__ states,
                const float* __restrict__ W0,
                const float* __restrict__ b0,
                const float* __restrict__ b1,
                const float* __restrict__ Wl,
                const float* __restrict__ bl,
                const __half* __restrict__ W1P,
                const __half* __restrict__ MP,
                float* __restrict__ out) {
    __shared__ __half   h1s[TILE * HD];                 // 64 KB, 16-row swizzled
    __shared__ uint8_t  wbuf[2][16][2][1024];           // 64 KB weight DMA ring
    __shared__ __align__(16) float red[16][TILE][4];    // 16 KB [qb][s][{dz0,dz1,dz2,tr}]
    __shared__ __align__(16) float wlb[HD][4];          // 8 KB  {Wl0,Wl1,Wl2,b1}
    __shared__ __align__(16) float xcs[TILE][4], xss[TILE][4], kss[TILE][4];
    __shared__ float bll[4];

    const int tid  = threadIdx.x;
    const int lane = tid & 63;
    const int wid  = tid >> 6;        // 0..15 = qb (K-loop) = p-tile (phase A)
    const int l31  = lane & 31;
    const int lhi  = lane >> 5;       // 0/1
    const int s0   = blockIdx.x * TILE;

    // ---- one-time staging ----
    if (tid < 4) bll[tid] = (tid < 3) ? bl[tid] : 0.f;
    if (tid < HD) {
        f32x4 w;
        w.x = Wl[tid * 3 + 0]; w.y = Wl[tid * 3 + 1]; w.z = Wl[tid * 3 + 2];
        w.w = b1[tid];
        *(f32x4*)&wlb[tid][0] = w;
    }
    if (tid < TILE * 4) {
        int s = tid >> 2, c = tid & 3;
        float v = states[(s0 + s) * 4 + c];
        xss[s][c] = v;
        xcs[s][c] = v;
    }

    // ---- persistent phase-A W0 fragment (A-operand, per-wave p-tile) ----
    // A[p][k] = W0ext[k][wid*32+p]; W0ext rows: k=0 -> b0, k=1 -> W0[t], k=2..4 -> W0[x], else 0
    U4 w0f;
    {
        int p = wid * 32 + l31;
        float v0 = b0[p];
        float v1 = W0[p];
        float v2 = W0[HD + p];
        float v3 = W0[2 * HD + p];
        float v4 = W0[3 * HD + p];
        w0f.u[0] = lhi ? 0u : pkh(v0, v1);
        w0f.u[1] = lhi ? 0u : pkh(v2, v3);
        w0f.u[2] = lhi ? 0u : pkh(v4, 0.f);
        w0f.u[3] = 0u;
    }

    // weight DMA sources (per-lane) and LDS ring bases (wave-uniform)
    const __half* w1src = W1P + wid * 16384 + lane * 8;
    const __half* msrc  = MP  + wid * 16384 + lane * 8;
    uint8_t* wb0 = &wbuf[0][wid][0][0];

    // prologue: slice 0 -> buf0, slice 1 -> buf1
    {
        __builtin_amdgcn_global_load_lds((glb_u32*)(w1src), (lds_u32*)(uintptr_t)(wb0), 16, 0, 0);
        __builtin_amdgcn_global_load_lds((glb_u32*)(msrc), (lds_u32*)(uintptr_t)(wb0 + 1024), 16, 0, 0);
        __builtin_amdgcn_global_load_lds((glb_u32*)(w1src + 512), (lds_u32*)(uintptr_t)(wb0 + 32768), 16, 0, 0);
        __builtin_amdgcn_global_load_lds((glb_u32*)(msrc + 512), (lds_u32*)(uintptr_t)(wb0 + 32768 + 1024), 16, 0, 0);
    }

    const int abase = l31 * HD + 8 * lhi;     // H-frag base (half elems), sample = l31
    const int aswz  = (l31 & 15) << 3;        // 16-row XOR swizzle (2-way max)
    const int wlbase = (wid * 32 + 4 * lhi);  // q base for phase C

    // phase-A write bases: frag0 sample = l31, frag1 sample = 32+l31; p-rows = wid*32+4*lhi+poff
    const int eb0 = l31 * HD + wid * 32 + 4 * lhi;
    const int eb1 = (32 + l31) * HD + wid * 32 + 4 * lhi;

    __syncthreads();

    const float hstp = 1.f / NSTEPS;
    const __half2 one2 = __floats2half2_rn(1.f, 1.f);

    for (int step = 0; step < NSTEPS; ++step) {
        float t0 = step * hstp;
        for (int stage = 0; stage < 4; ++stage) {
            float tEval = t0 + (stage == 0 ? 0.f : (stage == 3 ? hstp : 0.5f * hstp));

            // ---- phase A (MFMA): H1 = tanh(W0ext^T @ Z^T), Z = [1,t,x0,x1,x2,0..] ----
            {
                f32x4 xc0 = *(const f32x4*)&xcs[l31][0];
                f32x4 xc1 = *(const f32x4*)&xcs[32 + l31][0];
                uint32_t bt = pkh(1.f, tEval);
                U4 bf0, bf1;
                bf0.u[0] = lhi ? 0u : bt;
                bf0.u[1] = lhi ? 0u : pkh(xc0.x, xc0.y);
                bf0.u[2] = lhi ? 0u : pkh(xc0.z, 0.f);
                bf0.u[3] = 0u;
                bf1.u[0] = lhi ? 0u : bt;
                bf1.u[1] = lhi ? 0u : pkh(xc1.x, xc1.y);
                bf1.u[2] = lhi ? 0u : pkh(xc1.z, 0.f);
                bf1.u[3] = 0u;
                f32x16 aH0 = {}, aH1 = {};
                aH0 = __builtin_amdgcn_mfma_f32_32x32x16_f16(w0f.v, bf0.v, aH0, 0, 0, 0);
                aH1 = __builtin_amdgcn_mfma_f32_32x32x16_f16(w0f.v, bf1.v, aH1, 0, 0, 0);
                #pragma unroll
                for (int pr = 0; pr < 8; ++pr) {
                    int r = pr * 2;
                    int poff = (r & 3) + 8 * (r >> 2);   // 0,2,8,10,16,18,24,26
                    uint32_t pk0 = pkh(tanh_fast(aH0[r]), tanh_fast(aH0[r + 1]));
                    uint32_t pk1 = pkh(tanh_fast(aH1[r]), tanh_fast(aH1[r + 1]));
                    ((uint32_t*)h1s)[((eb0 + poff) ^ aswz) >> 1] = pk0;
                    ((uint32_t*)h1s)[((eb1 + poff) ^ aswz) >> 1] = pk1;
                }
            }
            __syncthreads();

            // ---- K-loop: accA = W1^T@H^T, accF = M^T@D^T; weights via LDS DMA ring ----
            // Restructured: H-reads/D-compute BEFORE vmcnt wait; lgkmcnt(0)+DMA AFTER MFMAs
            // (ring hazard still protected: lgkmcnt(0) precedes the overwrite DMA).
            f32x16 accA0 = {}, accA1 = {}, accF0 = {}, accF1 = {};

            #pragma unroll 4
            for (int kk = 0; kk < 32; ++kk) {
                const int buf = kk & 1;
                uint8_t* wbase = wb0 + buf * 32768;

                U4 wa, wm, H0, H1, D0, D1;
                int a0 = (abase + kk * 16) ^ aswz;
                H0.q = *(const uint4*)(h1s + a0);
                H1.q = *(const uint4*)(h1s + a0 + 32 * HD);
                #pragma unroll
                for (int i = 0; i < 4; ++i) {
                    D0.h[i] = __hfma2(__hneg2(H0.h[i]), H0.h[i], one2);   // 1 - h^2
                    D1.h[i] = __hfma2(__hneg2(H1.h[i]), H1.h[i], one2);
                }

                // slice kk resident when outstanding <= 2 (slice kk+1 in flight)
                asm volatile("s_waitcnt vmcnt(2)" ::: "memory");
                wa.q = *(const uint4*)(wbase + lane * 16);
                wm.q = *(const uint4*)(wbase + 1024 + lane * 16);

                __builtin_amdgcn_s_setprio(1);
                accA0 = __builtin_amdgcn_mfma_f32_32x32x16_f16(wa.v, H0.v, accA0, 0, 0, 0);
                accF0 = __builtin_amdgcn_mfma_f32_32x32x16_f16(wm.v, D0.v, accF0, 0, 0, 0);
                accA1 = __builtin_amdgcn_mfma_f32_32x32x16_f16(wa.v, H1.v, accA1, 0, 0, 0);
                accF1 = __builtin_amdgcn_mfma_f32_32x32x16_f16(wm.v, D1.v, accF1, 0, 0, 0);
                __builtin_amdgcn_s_setprio(0);

                // all ds_reads of this buf retired -> safe to overwrite with slice kk+2
                asm volatile("s_waitcnt lgkmcnt(0)" ::: "memory");
                {
                    int nk = (kk + 2) & 31;
                    __builtin_amdgcn_global_load_lds((glb_u32*)(w1src + nk * 512),
                        (lds_u32*)(uintptr_t)(wbase), 16, 0, 0);
                    __builtin_amdgcn_global_load_lds((glb_u32*)(msrc + nk * 512),
                        (lds_u32*)(uintptr_t)(wbase + 1024), 16, 0, 0);
                }
            }

            // ---- phase C: h2/d2 per q-row; in-lane q-reduction ----
            float dzA0 = 0.f, dzA1 = 0.f, dzA2 = 0.f, fdA = 0.f;   // sf0
            float dzB0 = 0.f, dzB1 = 0.f, dzB2 = 0.f, fdB = 0.f;   // sf1
            #pragma unroll
            for (int r = 0; r < 16; ++r) {
                f32x4 w = *(const f32x4*)&wlb[wlbase + (r & 3) + 8 * (r >> 2)][0];
                float h2a = tanh_fast(accA0[r] + w.w);
                float h2b = tanh_fast(accA1[r] + w.w);
                float d2a = __builtin_fmaf(-h2a, h2a, 1.f);
                float d2b = __builtin_fmaf(-h2b, h2b, 1.f);
                fdA  = __builtin_fmaf(accF0[r], d2a, fdA);
                fdB  = __builtin_fmaf(accF1[r], d2b, fdB);
                dzA0 = __builtin_fmaf(h2a, w.x, dzA0);
                dzA1 = __builtin_fmaf(h2a, w.y, dzA1);
                dzA2 = __builtin_fmaf(h2a, w.z, dzA2);
                dzB0 = __builtin_fmaf(h2b, w.x, dzB0);
                dzB1 = __builtin_fmaf(h2b, w.y, dzB1);
                dzB2 = __builtin_fmaf(h2b, w.z, dzB2);
            }
            // combine q-halves across lane^32
            dzA0 += __shfl_xor(dzA0, 32, 64);  dzB0 += __shfl_xor(dzB0, 32, 64);
            dzA1 += __shfl_xor(dzA1, 32, 64);  dzB1 += __shfl_xor(dzB1, 32, 64);
            dzA2 += __shfl_xor(dzA2, 32, 64);  dzB2 += __shfl_xor(dzB2, 32, 64);
            fdA  += __shfl_xor(fdA, 32, 64);   fdB  += __shfl_xor(fdB, 32, 64);

            {   // lhi=0 lanes write sample l31 (sf0); lhi=1 lanes write 32+l31 (sf1)
                int s_w = lhi * 32 + l31;
                f32x4 o;
                o.x = lhi ? dzB0 : dzA0;
                o.y = lhi ? dzB1 : dzA1;
                o.z = lhi ? dzB2 : dzA2;
                o.w = lhi ? fdB  : fdA;
                *(f32x4*)&red[wid][s_w][0] = o;
            }
            __syncthreads();

            // ---- combine: k = [dz + bl, -trace]; RK4 update ----
            if (tid < TILE * 4) {
                int s = tid >> 2, c = tid & 3;
                float k = 0.f;
                #pragma unroll
                for (int qb = 0; qb < 16; ++qb) k += red[qb][s][c];
                k = (c < 3) ? (k + bll[c]) : (-k);
                float xsv = xss[s][c];
                if (stage == 0)      { kss[s][c] = k;          xcs[s][c] = xsv + 0.5f * hstp * k; }
                else if (stage == 1) { kss[s][c] += 2.f * k;   xcs[s][c] = xsv + 0.5f * hstp * k; }
                else if (stage == 2) { kss[s][c] += 2.f * k;   xcs[s][c] = xsv + hstp * k; }
                else {
                    float nx = xsv + (hstp / 6.f) * (kss[s][c] + k);
                    xss[s][c] = nx; xcs[s][c] = nx;
                }
            }
            __syncthreads();
        }
    }

    if (tid < TILE * 4) {
        int s = tid >> 2, c = tid & 3;
        out[(s0 + s) * 4 + c] = xss[s][c];
    }
}

extern "C" void kernel_launch(void* const* d_in, const int* in_sizes, int n_in,
                              void* d_out, int out_size, void* d_ws, size_t ws_size,
                              hipStream_t stream) {
    const float* states = (const float*)d_in[0];
    const float* W0 = (const float*)d_in[1];
    const float* b0 = (const float*)d_in[2];
    const float* W1 = (const float*)d_in[3];
    const float* b1 = (const float*)d_in[4];
    const float* Wl = (const float*)d_in[5];
    const float* bl = (const float*)d_in[6];
    float* out = (float*)d_out;

    __half* W1P = (__half*)d_ws;                 // 512*512 f16 = 512 KB
    __half* MP  = W1P + HD * HD;                 // +512 KB (total 1 MB)

    prep_kernel<<<(HD * HD) / 256, 256, 0, stream>>>(W1, W0, Wl, W1P, MP);

    const int B = in_sizes[0] / 4;               // 65536
    ode_kernel<<<B / TILE, NT, 0, stream>>>(states, W0, b0, b1, Wl, bl, W1P, MP, out);
}

// Round 16
// 452.092 us; speedup vs baseline: 1.0226x; 1.0226x over previous
//
#include <hip/hip_runtime.h>
#include <hip/hip_fp16.h>
#include <stdint.h>

#define HD 512
#define TILE 64
#define NSTEPS 1
#define NT 1024

typedef float    f32x16 __attribute__((ext_vector_type(16)));
typedef float    f32x4  __attribute__((ext_vector_type(4)));
typedef _Float16 f16x8  __attribute__((ext_vector_type(8)));

typedef __attribute__((address_space(3))) uint32_t lds_u32;
typedef __attribute__((address_space(1))) const uint32_t glb_u32;

__device__ __forceinline__ float tanh_fast(float x) {
    float e = __builtin_amdgcn_exp2f(x * 2.885390081777927f);   // e^{2x}
    return __builtin_fmaf(-2.f, __builtin_amdgcn_rcpf(1.f + e), 1.f);
}

__device__ __forceinline__ uint32_t pkh(float lo, float hi) {
    return __builtin_bit_cast(uint32_t, __builtin_amdgcn_cvt_pkrtz(lo, hi));
}

// Packed fragment-ordered weights:
//   WP[idx], idx = ((qb*32 + kk)*64 + lane)*8 + j
//   value = W[p][q],  p = kk*16 + (lane>>5)*8 + j,  q = qb*32 + (lane&31)
__global__ void prep_kernel(const float* __restrict__ W1,
                            const float* __restrict__ W0,
                            const float* __restrict__ Wl,
                            __half* __restrict__ W1P,
                            __half* __restrict__ MP) {
    int idx = blockIdx.x * 256 + threadIdx.x;     // 0 .. 512*512-1
    int j    = idx & 7;
    int lane = (idx >> 3) & 63;
    int kk   = (idx >> 9) & 31;
    int qb   = idx >> 14;
    int p = kk * 16 + (lane >> 5) * 8 + j;
    int q = qb * 32 + (lane & 31);
    float w = W1[p * HD + q];
    float c = W0[HD + p]     * Wl[q * 3 + 0]
            + W0[2 * HD + p] * Wl[q * 3 + 1]
            + W0[3 * HD + p] * Wl[q * 3 + 2];
    W1P[idx] = __float2half(w);
    MP[idx]  = __float2half(w * c);
}

union U4 { uint4 q; f16x8 v; __half2 h[4]; uint32_t u[4]; };

__global__ __launch_bounds__(NT, 4)
void ode_kernel(const float* __restrict__ states,
                const float* __restrict__ W0,
                const float* __restrict__ b0,
                const float* __restrict__ b1,
                const float* __restrict__ Wl,
                const float* __restrict__ bl,
                const __half* __restrict__ W1P,
                const __half* __restrict__ MP,
                float* __restrict__ out) {
    __shared__ __half   h1s[TILE * HD];                 // 64 KB, 16-row swizzled
    __shared__ uint8_t  wbuf[2][16][2][1024];           // 64 KB weight DMA ring
    __shared__ __align__(16) float red[16][TILE][4];    // 16 KB [qb][s][{dz0,dz1,dz2,tr}]
    __shared__ __align__(16) float wlb[HD][4];          // 8 KB  {Wl0,Wl1,Wl2,b1}
    __shared__ __align__(16) float xcs[TILE][4], xss[TILE][4], kss[TILE][4];
    __shared__ float bll[4];

    const int tid  = threadIdx.x;
    const int lane = tid & 63;
    const int wid  = tid >> 6;        // 0..15 = qb (K-loop) = p-tile (phase A)
    const int l31  = lane & 31;
    const int lhi  = lane >> 5;       // 0/1
    const int s0   = blockIdx.x * TILE;

    // ---- one-time staging ----
    if (tid < 4) bll[tid] = (tid < 3) ? bl[tid] : 0.f;
    if (tid < HD) {
        f32x4 w;
        w.x = Wl[tid * 3 + 0]; w.y = Wl[tid * 3 + 1]; w.z = Wl[tid * 3 + 2];
        w.w = b1[tid];
        *(f32x4*)&wlb[tid][0] = w;
    }
    if (tid < TILE * 4) {
        int s = tid >> 2, c = tid & 3;
        float v = states[(s0 + s) * 4 + c];
        xss[s][c] = v;
        xcs[s][c] = v;
    }

    // ---- persistent phase-A W0 fragment (A-operand, per-wave p-tile) ----
    // A[p][k] = W0ext[k][wid*32+p]; W0ext rows: k=0 -> b0, k=1 -> W0[t], k=2..4 -> W0[x], else 0
    U4 w0f;
    {
        int p = wid * 32 + l31;
        float v0 = b0[p];
        float v1 = W0[p];
        float v2 = W0[HD + p];
        float v3 = W0[2 * HD + p];
        float v4 = W0[3 * HD + p];
        w0f.u[0] = lhi ? 0u : pkh(v0, v1);
        w0f.u[1] = lhi ? 0u : pkh(v2, v3);
        w0f.u[2] = lhi ? 0u : pkh(v4, 0.f);
        w0f.u[3] = 0u;
    }

    // weight DMA sources (per-lane) and LDS ring bases (wave-uniform)
    const __half* w1src = W1P + wid * 16384 + lane * 8;
    const __half* msrc  = MP  + wid * 16384 + lane * 8;
    uint8_t* wb0 = &wbuf[0][wid][0][0];

    // prologue: slice 0 -> buf0, slice 1 -> buf1
    {
        __builtin_amdgcn_global_load_lds((glb_u32*)(w1src), (lds_u32*)(uintptr_t)(wb0), 16, 0, 0);
        __builtin_amdgcn_global_load_lds((glb_u32*)(msrc), (lds_u32*)(uintptr_t)(wb0 + 1024), 16, 0, 0);
        __builtin_amdgcn_global_load_lds((glb_u32*)(w1src + 512), (lds_u32*)(uintptr_t)(wb0 + 32768), 16, 0, 0);
        __builtin_amdgcn_global_load_lds((glb_u32*)(msrc + 512), (lds_u32*)(uintptr_t)(wb0 + 32768 + 1024), 16, 0, 0);
    }

    const int abase = l31 * HD + 8 * lhi;     // H-frag base (half elems), sample = l31
    const int aswz  = (l31 & 15) << 3;        // 16-row XOR swizzle (2-way max)
    const int wlbase = (wid * 32 + 4 * lhi);  // q base for phase C

    // phase-A write bases: frag0 sample = l31, frag1 sample = 32+l31; p-rows = wid*32+4*lhi+poff
    const int eb0 = l31 * HD + wid * 32 + 4 * lhi;
    const int eb1 = (32 + l31) * HD + wid * 32 + 4 * lhi;

    __syncthreads();

    const float hstp = 1.f / NSTEPS;
    const __half2 one2 = __floats2half2_rn(1.f, 1.f);

    for (int step = 0; step < NSTEPS; ++step) {
        float t0 = step * hstp;
        for (int stage = 0; stage < 4; ++stage) {
            float tEval = t0 + (stage == 0 ? 0.f : (stage == 3 ? hstp : 0.5f * hstp));

            // ---- phase A (MFMA): H1 = tanh(W0ext^T @ Z^T), Z = [1,t,x0,x1,x2,0..] ----
            {
                f32x4 xc0 = *(const f32x4*)&xcs[l31][0];
                f32x4 xc1 = *(const f32x4*)&xcs[32 + l31][0];
                uint32_t bt = pkh(1.f, tEval);
                U4 bf0, bf1;
                bf0.u[0] = lhi ? 0u : bt;
                bf0.u[1] = lhi ? 0u : pkh(xc0.x, xc0.y);
                bf0.u[2] = lhi ? 0u : pkh(xc0.z, 0.f);
                bf0.u[3] = 0u;
                bf1.u[0] = lhi ? 0u : bt;
                bf1.u[1] = lhi ? 0u : pkh(xc1.x, xc1.y);
                bf1.u[2] = lhi ? 0u : pkh(xc1.z, 0.f);
                bf1.u[3] = 0u;
                f32x16 aH0 = {}, aH1 = {};
                aH0 = __builtin_amdgcn_mfma_f32_32x32x16_f16(w0f.v, bf0.v, aH0, 0, 0, 0);
                aH1 = __builtin_amdgcn_mfma_f32_32x32x16_f16(w0f.v, bf1.v, aH1, 0, 0, 0);
                #pragma unroll
                for (int pr = 0; pr < 8; ++pr) {
                    int r = pr * 2;
                    int poff = (r & 3) + 8 * (r >> 2);   // 0,2,8,10,16,18,24,26
                    uint32_t pk0 = pkh(tanh_fast(aH0[r]), tanh_fast(aH0[r + 1]));
                    uint32_t pk1 = pkh(tanh_fast(aH1[r]), tanh_fast(aH1[r + 1]));
                    ((uint32_t*)h1s)[((eb0 + poff) ^ aswz) >> 1] = pk0;
                    ((uint32_t*)h1s)[((eb1 + poff) ^ aswz) >> 1] = pk1;
                }
            }
            __syncthreads();

            // ---- K-loop: accA = W1^T@H^T, accF = M^T@D^T; weights via LDS DMA ring ----
            // R14 structure (drain early, DMA early); only change: lgkmcnt(2) instead of
            // lgkmcnt(0) — wa/wm are pinned oldest, so the ring-overwrite hazard is still
            // exactly covered while the H-reads stay in flight.
            f32x16 accA0 = {}, accA1 = {}, accF0 = {}, accF1 = {};

            #pragma unroll 4
            for (int kk = 0; kk < 32; ++kk) {
                const int buf = kk & 1;
                uint8_t* wbase = wb0 + buf * 32768;

                // slice kk resident when outstanding <= 2 (slice kk+1 in flight)
                asm volatile("s_waitcnt vmcnt(2)" ::: "memory");
                __builtin_amdgcn_sched_barrier(0);

                U4 wa, wm, H0, H1, D0, D1;
                wa.q = *(const uint4*)(wbase + lane * 16);
                wm.q = *(const uint4*)(wbase + 1024 + lane * 16);
                __builtin_amdgcn_sched_barrier(0);   // pin wa/wm as the 2 oldest DS ops
                int a0 = (abase + kk * 16) ^ aswz;
                H0.q = *(const uint4*)(h1s + a0);
                H1.q = *(const uint4*)(h1s + a0 + 32 * HD);

                // wa/wm retired (DS retires in order) -> safe to overwrite this buf
                asm volatile("s_waitcnt lgkmcnt(2)" ::: "memory");
                __builtin_amdgcn_sched_barrier(0);
                {
                    int nk = (kk + 2) & 31;
                    __builtin_amdgcn_global_load_lds((glb_u32*)(w1src + nk * 512),
                        (lds_u32*)(uintptr_t)(wbase), 16, 0, 0);
                    __builtin_amdgcn_global_load_lds((glb_u32*)(msrc + nk * 512),
                        (lds_u32*)(uintptr_t)(wbase + 1024), 16, 0, 0);
                }

                #pragma unroll
                for (int i = 0; i < 4; ++i) {
                    D0.h[i] = __hfma2(__hneg2(H0.h[i]), H0.h[i], one2);   // 1 - h^2
                    D1.h[i] = __hfma2(__hneg2(H1.h[i]), H1.h[i], one2);
                }
                __builtin_amdgcn_s_setprio(1);
                accA0 = __builtin_amdgcn_mfma_f32_32x32x16_f16(wa.v, H0.v, accA0, 0, 0, 0);
                accF0 = __builtin_amdgcn_mfma_f32_32x32x16_f16(wm.v, D0.v, accF0, 0, 0, 0);
                accA1 = __builtin_amdgcn_mfma_f32_32x32x16_f16(wa.v, H1.v, accA1, 0, 0, 0);
                accF1 = __builtin_amdgcn_mfma_f32_32x32x16_f16(wm.v, D1.v, accF1, 0, 0, 0);
                __builtin_amdgcn_s_setprio(0);
            }

            // ---- phase C: h2/d2 per q-row; in-lane q-reduction ----
            float dzA0 = 0.f, dzA1 = 0.f, dzA2 = 0.f, fdA = 0.f;   // sf0
            float dzB0 = 0.f, dzB1 = 0.f, dzB2 = 0.f, fdB = 0.f;   // sf1
            #pragma unroll
            for (int r = 0; r < 16; ++r) {
                f32x4 w = *(const f32x4*)&wlb[wlbase + (r & 3) + 8 * (r >> 2)][0];
                float h2a = tanh_fast(accA0[r] + w.w);
                float h2b = tanh_fast(accA1[r] + w.w);
                float d2a = __builtin_fmaf(-h2a, h2a, 1.f);
                float d2b = __builtin_fmaf(-h2b, h2b, 1.f);
                fdA  = __builtin_fmaf(accF0[r], d2a, fdA);
                fdB  = __builtin_fmaf(accF1[r], d2b, fdB);
                dzA0 = __builtin_fmaf(h2a, w.x, dzA0);
                dzA1 = __builtin_fmaf(h2a, w.y, dzA1);
                dzA2 = __builtin_fmaf(h2a, w.z, dzA2);
                dzB0 = __builtin_fmaf(h2b, w.x, dzB0);
                dzB1 = __builtin_fmaf(h2b, w.y, dzB1);
                dzB2 = __builtin_fmaf(h2b, w.z, dzB2);
            }
            // combine q-halves across lane^32
            dzA0 += __shfl_xor(dzA0, 32, 64);  dzB0 += __shfl_xor(dzB0, 32, 64);
            dzA1 += __shfl_xor(dzA1, 32, 64);  dzB1 += __shfl_xor(dzB1, 32, 64);
            dzA2 += __shfl_xor(dzA2, 32, 64);  dzB2 += __shfl_xor(dzB2, 32, 64);
            fdA  += __shfl_xor(fdA, 32, 64);   fdB  += __shfl_xor(fdB, 32, 64);

            {   // lhi=0 lanes write sample l31 (sf0); lhi=1 lanes write 32+l31 (sf1)
                int s_w = lhi * 32 + l31;
                f32x4 o;
                o.x = lhi ? dzB0 : dzA0;
                o.y = lhi ? dzB1 : dzA1;
                o.z = lhi ? dzB2 : dzA2;
                o.w = lhi ? fdB  : fdA;
                *(f32x4*)&red[wid][s_w][0] = o;
            }
            __syncthreads();

            // ---- combine: k = [dz + bl, -trace]; RK4 update ----
            if (tid < TILE * 4) {
                int s = tid >> 2, c = tid & 3;
                float k = 0.f;
                #pragma unroll
                for (int qb = 0; qb < 16; ++qb) k += red[qb][s][c];
                k = (c < 3) ? (k + bll[c]) : (-k);
                float xsv = xss[s][c];
                if (stage == 0)      { kss[s][c] = k;          xcs[s][c] = xsv + 0.5f * hstp * k; }
                else if (stage == 1) { kss[s][c] += 2.f * k;   xcs[s][c] = xsv + 0.5f * hstp * k; }
                else if (stage == 2) { kss[s][c] += 2.f * k;   xcs[s][c] = xsv + hstp * k; }
                else {
                    float nx = xsv + (hstp / 6.f) * (kss[s][c] + k);
                    xss[s][c] = nx; xcs[s][c] = nx;
                }
            }
            __syncthreads();
        }
    }

    if (tid < TILE * 4) {
        int s = tid >> 2, c = tid & 3;
        out[(s0 + s) * 4 + c] = xss[s][c];
    }
}

extern "C" void kernel_launch(void* const* d_in, const int* in_sizes, int n_in,
                              void* d_out, int out_size, void* d_ws, size_t ws_size,
                              hipStream_t stream) {
    const float* states = (const float*)d_in[0];
    const float* W0 = (const float*)d_in[1];
    const float* b0 = (const float*)d_in[2];
    const float* W1 = (const float*)d_in[3];
    const float* b1 = (const float*)d_in[4];
    const float* Wl = (const float*)d_in[5];
    const float* bl = (const float*)d_in[6];
    float* out = (float*)d_out;

    __half* W1P = (__half*)d_ws;                 // 512*512 f16 = 512 KB
    __half* MP  = W1P + HD * HD;                 // +512 KB (total 1 MB)

    prep_kernel<<<(HD * HD) / 256, 256, 0, stream>>>(W1, W0, Wl, W1P, MP);

    const int B = in_sizes[0] / 4;               // 65536
    ode_kernel<<<B / TILE, NT, 0, stream>>>(states, W0, b0, b1, Wl, bl, W1P, MP, out);
}